// Round 1
// baseline (629.384 us; speedup 1.0000x reference)
//
#include <hip/hip_runtime.h>
#include <stdint.h>

#define NH 16
#define DH 64
#define DE 1024
#define DC 768
#define NB 8
#define SQL 4096
#define SKV 77

typedef __attribute__((ext_vector_type(8))) short s16x8;
typedef __attribute__((ext_vector_type(4))) float f32x4;

__device__ inline ushort f2b(float f) {
    union { float f; uint32_t u; } v; v.f = f;
    uint32_t u = v.u;
    uint32_t r = (u + 0x7FFFu + ((u >> 16) & 1u)) >> 16;
    return (ushort)r;
}

__device__ inline void gload_lds16(const void* g, void* l) {
    __builtin_amdgcn_global_load_lds(
        (const __attribute__((address_space(1))) void*)g,
        (__attribute__((address_space(3))) void*)l, 16, 0, 0);
}

// ---------------- fp32 -> bf16 convert (vectorized) ----------------
__global__ void cvt_f32_bf16(const float* __restrict__ in, ushort* __restrict__ out,
                             long long n) {
    long long i = ((long long)blockIdx.x * 256 + threadIdx.x) * 8;
    if (i >= n) return;
    float4 a = *(const float4*)(in + i);
    float4 b = *(const float4*)(in + i + 4);
    ushort4 r0 = make_ushort4(f2b(a.x), f2b(a.y), f2b(a.z), f2b(a.w));
    ushort4 r1 = make_ushort4(f2b(b.x), f2b(b.y), f2b(b.z), f2b(b.w));
    *(ushort4*)(out + i) = r0;
    *(ushort4*)(out + i + 4) = r1;
}

// ---------------- transpose + convert: in fp32 [K][N] -> out bf16 [N][K] ----
__global__ void transpose_cvt(const float* __restrict__ in, ushort* __restrict__ out,
                              int K, int N) {
    __shared__ float tile[32][33];
    const int tx = threadIdx.x, ty = threadIdx.y;      // (32, 8)
    const int bn = blockIdx.x * 32, bk = blockIdx.y * 32;
#pragma unroll
    for (int i = 0; i < 4; ++i)
        tile[ty + i * 8][tx] = in[(size_t)(bk + ty + i * 8) * N + bn + tx];
    __syncthreads();
#pragma unroll
    for (int i = 0; i < 4; ++i)
        out[(size_t)(bn + ty + i * 8) * K + bk + tx] = f2b(tile[tx][ty + i * 8]);
}

// ---------------- pack bk|bv into one 2048-float bias ----------------
__global__ void pack_bias(const float* __restrict__ bk, const float* __restrict__ bv,
                          float* __restrict__ bkv) {
    int i = blockIdx.x * 256 + threadIdx.x;
    if (i < 2048) bkv[i] = (i < 1024) ? bk[i] : bv[i - 1024];
}

// ---------------- 128x128 bf16 GEMM (m97 structure): C = A @ Bt^T + bias ----
// A: [M][K] bf16, Bt: [N][K] bf16, OUTBF=1 -> bf16 out (acc+bias)*scale, else f32
template <int OUTBF>
__global__ __launch_bounds__(256, 2)
void gemm_bt(const ushort* __restrict__ A, const ushort* __restrict__ Bt,
             const float* __restrict__ bias, void* __restrict__ Cout,
             int M, int N, int K, int Mvalid, float scale) {
    __shared__ ushort As[128][32];
    __shared__ ushort Bs[128][32];
    const int tid = threadIdx.x;
    const int lane = tid & 63, wid = tid >> 6;
    const int wr = wid >> 1, wc = wid & 1;
    const int row0 = blockIdx.x * 128, col0 = blockIdx.y * 128;

    const int srow = tid >> 2;         // staging row 0..63
    const int sk = (tid & 3) * 8;      // staging k-offset (elems)
    const ushort* Ag = A + (size_t)(row0 + srow) * K + sk;
    const ushort* Bg = Bt + (size_t)(col0 + srow) * K + sk;
    ushort* Asl = &As[srow][sk];
    ushort* Asl2 = &As[srow + 64][sk];
    ushort* Bsl = &Bs[srow][sk];
    ushort* Bsl2 = &Bs[srow + 64][sk];
    const size_t rstep = (size_t)64 * K;

    f32x4 acc[4][4] = {};
    const int mrow = wr * 64 + (lane & 15);
    const int ncol = wc * 64 + (lane & 15);
    const int kfr = (lane >> 4) * 8;

    const int nk = K >> 5;
    for (int kt = 0; kt < nk; ++kt) {
        gload_lds16(Ag, Asl);
        gload_lds16(Ag + rstep, Asl2);
        gload_lds16(Bg, Bsl);
        gload_lds16(Bg + rstep, Bsl2);
        Ag += 32; Bg += 32;
        __syncthreads();   // drains vmcnt: staging complete
        s16x8 af[4], bfr[4];
#pragma unroll
        for (int m = 0; m < 4; ++m)
            af[m] = *(const s16x8*)&As[mrow + m * 16][kfr];
#pragma unroll
        for (int n = 0; n < 4; ++n)
            bfr[n] = *(const s16x8*)&Bs[ncol + n * 16][kfr];
#pragma unroll
        for (int m = 0; m < 4; ++m)
#pragma unroll
            for (int n = 0; n < 4; ++n)
                acc[m][n] = __builtin_amdgcn_mfma_f32_16x16x32_bf16(
                    af[m], bfr[n], acc[m][n], 0, 0, 0);
        __syncthreads();   // all reads done before next stage
    }

    const int r0 = row0 + wr * 64 + ((lane >> 4) << 2);
    const int c0 = col0 + wc * 64 + (lane & 15);
#pragma unroll
    for (int n = 0; n < 4; ++n) {
        const int c = c0 + n * 16;
        const float bv = bias[c];
#pragma unroll
        for (int m = 0; m < 4; ++m) {
#pragma unroll
            for (int r = 0; r < 4; ++r) {
                const int row = r0 + m * 16 + r;
                if (row < Mvalid) {
                    float v = acc[m][n][r] + bv;
                    if (OUTBF)
                        ((ushort*)Cout)[(size_t)row * N + c] = f2b(v * scale);
                    else
                        ((float*)Cout)[(size_t)row * N + c] = v;
                }
            }
        }
    }
}

// ---------------- fused attention: per (b,h, 64-row q tile) ----------------
// q: [B*SQ][DE] bf16 (pre-scaled by 1/8, bias fused)
// kv: [640][2048] bf16 rows b*77+s; cols 0..1023 = K heads, 1024..2047 = V heads
// o: [B*SQ][DE] bf16
__global__ __launch_bounds__(256, 2)
void attn(const ushort* __restrict__ q, const ushort* __restrict__ kv,
          ushort* __restrict__ o) {
    __shared__ ushort Ks[80][64];   // rows 77..79 garbage (never read post-softmax)
    __shared__ ushort Vt[64][96];   // V^T, cols 77..95 zeroed
    __shared__ float Ss[64][80];
    __shared__ ushort Ps[64][96];

    const int qt = blockIdx.x;
    const int bh = blockIdx.y;
    const int b = bh >> 4, h = bh & 15;
    const int tid = threadIdx.x, lane = tid & 63, wid = tid >> 6;

    const ushort* kbase = kv + (size_t)b * SKV * 2048 + h * 64;
    const ushort* vbase = kbase + 1024;

    // zero Vt (pad safety: 0 * P(=0) pad products, no NaN)
    {
        uint32_t* p = (uint32_t*)&Vt[0][0];  // 64*96/2 = 3072 dwords
        for (int i = tid; i < 3072; i += 256) p[i] = 0;
    }
    __syncthreads();
    // stage K rows [77][64]
    {
        int row = tid >> 3;
        const int cs = (tid & 7) * 8;
#pragma unroll
        for (int pass = 0; pass < 3; ++pass, row += 32)
            if (row < SKV)
                *(uint4*)&Ks[row][cs] = *(const uint4*)(kbase + (size_t)row * 2048 + cs);
    }
    // stage V transposed
    for (int t = tid; t < SKV * 8; t += 256) {
        const int s = t >> 3, d8 = (t & 7) * 8;
        const ushort* src = vbase + (size_t)s * 2048 + d8;
#pragma unroll
        for (int j = 0; j < 8; ++j) Vt[d8 + j][s] = src[j];
    }
    // Q fragments straight from global (each wave owns 16 q-rows)
    const int qrow = b * SQL + qt * 64 + wid * 16 + (lane & 15);
    const int kfr = (lane >> 4) * 8;
    s16x8 aq0 = *(const s16x8*)(q + (size_t)qrow * DE + h * 64 + kfr);
    s16x8 aq1 = *(const s16x8*)(q + (size_t)qrow * DE + h * 64 + kfr + 32);
    __syncthreads();

    // S = Qs @ K^T  (80 padded cols)
    f32x4 accs[5] = {};
#pragma unroll
    for (int n = 0; n < 5; ++n) {
        s16x8 b0 = *(const s16x8*)&Ks[n * 16 + (lane & 15)][kfr];
        s16x8 b1 = *(const s16x8*)&Ks[n * 16 + (lane & 15)][kfr + 32];
        accs[n] = __builtin_amdgcn_mfma_f32_16x16x32_bf16(aq0, b0, accs[n], 0, 0, 0);
        accs[n] = __builtin_amdgcn_mfma_f32_16x16x32_bf16(aq1, b1, accs[n], 0, 0, 0);
    }
    const int srow = wid * 16 + ((lane >> 4) << 2);
#pragma unroll
    for (int n = 0; n < 5; ++n)
#pragma unroll
        for (int r = 0; r < 4; ++r)
            Ss[srow + r][n * 16 + (lane & 15)] = accs[n][r];
    __syncthreads();

    // softmax: 4 threads per row over 77 cols
    {
        const int row = tid >> 2, part = tid & 3;
        float m = -1e30f;
        for (int j = part; j < SKV; j += 4) m = fmaxf(m, Ss[row][j]);
        m = fmaxf(m, __shfl_xor(m, 1));
        m = fmaxf(m, __shfl_xor(m, 2));
        float s = 0.f;
        for (int j = part; j < SKV; j += 4) {
            float e = __expf(Ss[row][j] - m);
            Ss[row][j] = e;
            s += e;
        }
        s += __shfl_xor(s, 1);
        s += __shfl_xor(s, 2);
        const float inv = 1.f / s;
        for (int j = part; j < 96; j += 4)
            Ps[row][j] = (j < SKV) ? f2b(Ss[row][j] * inv) : (ushort)0;
    }
    __syncthreads();

    // O = P @ V  (K = 96, zero-padded)
    f32x4 acco[4] = {};
#pragma unroll
    for (int kk = 0; kk < 3; ++kk) {
        s16x8 ap = *(const s16x8*)&Ps[wid * 16 + (lane & 15)][kk * 32 + kfr];
#pragma unroll
        for (int n = 0; n < 4; ++n) {
            s16x8 bv = *(const s16x8*)&Vt[n * 16 + (lane & 15)][kk * 32 + kfr];
            acco[n] = __builtin_amdgcn_mfma_f32_16x16x32_bf16(ap, bv, acco[n], 0, 0, 0);
        }
    }
    const int orow = b * SQL + qt * 64 + srow;
#pragma unroll
    for (int n = 0; n < 4; ++n)
#pragma unroll
        for (int r = 0; r < 4; ++r)
            o[(size_t)(orow + r) * DE + h * 64 + n * 16 + (lane & 15)] = f2b(acco[n][r]);
}

extern "C" void kernel_launch(void* const* d_in, const int* in_sizes, int n_in,
                              void* d_out, int out_size, void* d_ws, size_t ws_size,
                              hipStream_t stream) {
    const float* x = (const float*)d_in[0];
    const float* y = (const float*)d_in[1];
    const float* wq = (const float*)d_in[2];
    const float* bq = (const float*)d_in[3];
    const float* wk = (const float*)d_in[4];
    const float* bk = (const float*)d_in[5];
    const float* wv = (const float*)d_in[6];
    const float* bv = (const float*)d_in[7];
    const float* wo = (const float*)d_in[8];
    const float* bo = (const float*)d_in[9];
    float* out = (float*)d_out;

    char* ws = (char*)d_ws;
    ushort* x16 = (ushort*)ws;  ws += (size_t)32768 * 1024 * 2;  // reused as attn_out
    ushort* q16 = (ushort*)ws;  ws += (size_t)32768 * 1024 * 2;
    ushort* y16 = (ushort*)ws;  ws += (size_t)640 * 768 * 2;     // padded M
    ushort* kv16 = (ushort*)ws; ws += (size_t)640 * 2048 * 2;    // padded M
    ushort* wqt = (ushort*)ws;  ws += (size_t)1024 * 1024 * 2;
    ushort* wkvt = (ushort*)ws; ws += (size_t)2048 * 768 * 2;
    ushort* wot = (ushort*)ws;  ws += (size_t)1024 * 1024 * 2;
    float* bkv = (float*)ws;    ws += 2048 * 4;

    // converts
    cvt_f32_bf16<<<16384, 256, 0, stream>>>(x, x16, 33554432LL);
    cvt_f32_bf16<<<231, 256, 0, stream>>>(y, y16, 473088LL);
    // weight transposes ([K][N] fp32 -> [N][K] bf16)
    transpose_cvt<<<dim3(32, 32), dim3(32, 8), 0, stream>>>(wq, wqt, 1024, 1024);
    transpose_cvt<<<dim3(32, 24), dim3(32, 8), 0, stream>>>(wk, wkvt, 768, 1024);
    transpose_cvt<<<dim3(32, 24), dim3(32, 8), 0, stream>>>(wv, wkvt + (size_t)1024 * 768, 768, 1024);
    transpose_cvt<<<dim3(32, 32), dim3(32, 8), 0, stream>>>(wo, wot, 1024, 1024);
    pack_bias<<<8, 256, 0, stream>>>(bk, bv, bkv);
    // K/V projection (combined): [640]x[2048], K=768, valid M=616
    gemm_bt<1><<<dim3(5, 16), 256, 0, stream>>>(y16, wkvt, bkv, kv16, 640, 2048, 768, 616, 1.0f);
    // Q projection, bias fused, pre-scaled by 1/sqrt(64)
    gemm_bt<1><<<dim3(256, 8), 256, 0, stream>>>(x16, wqt, bq, q16, 32768, 1024, 1024, 32768, 0.125f);
    // attention (attn_out aliases x16; x16 dead after Q-proj)
    attn<<<dim3(64, 128), 256, 0, stream>>>(q16, kv16, x16);
    // output projection -> fp32 out
    gemm_bt<0><<<dim3(256, 8), 256, 0, stream>>>(x16, wot, bo, out, 32768, 1024, 1024, 32768, 1.0f);
}

// Round 2
// 525.829 us; speedup vs baseline: 1.1969x; 1.1969x over previous
//
#include <hip/hip_runtime.h>
#include <stdint.h>

#define NH 16
#define DH 64
#define DE 1024
#define DC 768
#define NB 8
#define SQL 4096
#define SKV 77
#define QCH 512

typedef __attribute__((ext_vector_type(8))) short s16x8;
typedef __attribute__((ext_vector_type(4))) float f32x4;

__device__ inline ushort f2b(float f) {
    union { float f; uint32_t u; } v; v.f = f;
    uint32_t u = v.u;
    uint32_t r = (u + 0x7FFFu + ((u >> 16) & 1u)) >> 16;
    return (ushort)r;
}

__device__ inline void gload_lds16(const void* g, void* l) {
    __builtin_amdgcn_global_load_lds(
        (const __attribute__((address_space(1))) void*)g,
        (__attribute__((address_space(3))) void*)l, 16, 0, 0);
}

// ---------------- fp32 -> bf16 convert (vectorized) ----------------
__global__ void cvt_f32_bf16(const float* __restrict__ in, ushort* __restrict__ out,
                             long long n) {
    long long i = ((long long)blockIdx.x * 256 + threadIdx.x) * 8;
    if (i >= n) return;
    float4 a = *(const float4*)(in + i);
    float4 b = *(const float4*)(in + i + 4);
    ushort4 r0 = make_ushort4(f2b(a.x), f2b(a.y), f2b(a.z), f2b(a.w));
    ushort4 r1 = make_ushort4(f2b(b.x), f2b(b.y), f2b(b.z), f2b(b.w));
    *(ushort4*)(out + i) = r0;
    *(ushort4*)(out + i + 4) = r1;
}

// ---------------- transpose + convert: in fp32 [K][N] -> out bf16 [N][K] ----
__global__ void transpose_cvt(const float* __restrict__ in, ushort* __restrict__ out,
                              int K, int N) {
    __shared__ float tile[32][33];
    const int tx = threadIdx.x, ty = threadIdx.y;      // (32, 8)
    const int bn = blockIdx.x * 32, bk = blockIdx.y * 32;
#pragma unroll
    for (int i = 0; i < 4; ++i)
        tile[ty + i * 8][tx] = in[(size_t)(bk + ty + i * 8) * N + bn + tx];
    __syncthreads();
#pragma unroll
    for (int i = 0; i < 4; ++i)
        out[(size_t)(bn + ty + i * 8) * K + bk + tx] = f2b(tile[tx][ty + i * 8]);
}

// ---------------- pack bk|bv into one 2048-float bias ----------------
__global__ void pack_bias(const float* __restrict__ bk, const float* __restrict__ bv,
                          float* __restrict__ bkv) {
    int i = blockIdx.x * 256 + threadIdx.x;
    if (i < 2048) bkv[i] = (i < 1024) ? bk[i] : bv[i - 1024];
}

// ---------------- 128x128 bf16 GEMM (m97 structure): C = A @ Bt^T + bias ----
// 1-D grid (multiple of 8), XCD-chunked swizzle; nby = # of col blocks.
template <int OUTBF>
__global__ __launch_bounds__(256, 2)
void gemm_bt(const ushort* __restrict__ A, const ushort* __restrict__ Bt,
             const float* __restrict__ bias, void* __restrict__ Cout,
             int M, int N, int K, int Mvalid, float scale, int nby) {
    __shared__ ushort As[128][32];
    __shared__ ushort Bs[128][32];
    const int tid = threadIdx.x;
    const int lane = tid & 63, wid = tid >> 6;
    const int wr = wid >> 1, wc = wid & 1;
    // XCD-chunked remap: 8 consecutive works (one A row-panel) -> one XCD
    const int l = blockIdx.x;
    const int q8 = gridDim.x >> 3;
    const int rm = (l & 7) * q8 + (l >> 3);
    const int row0 = (rm / nby) * 128, col0 = (rm % nby) * 128;

    const int srow = tid >> 2;         // staging row 0..63
    const int sk = (tid & 3) * 8;      // staging k-offset (elems)
    const ushort* Ag = A + (size_t)(row0 + srow) * K + sk;
    const ushort* Bg = Bt + (size_t)(col0 + srow) * K + sk;
    ushort* Asl = &As[srow][sk];
    ushort* Asl2 = &As[srow + 64][sk];
    ushort* Bsl = &Bs[srow][sk];
    ushort* Bsl2 = &Bs[srow + 64][sk];
    const size_t rstep = (size_t)64 * K;

    f32x4 acc[4][4] = {};
    const int mrow = wr * 64 + (lane & 15);
    const int ncol = wc * 64 + (lane & 15);
    const int kfr = (lane >> 4) * 8;

    const int nk = K >> 5;
    for (int kt = 0; kt < nk; ++kt) {
        gload_lds16(Ag, Asl);
        gload_lds16(Ag + rstep, Asl2);
        gload_lds16(Bg, Bsl);
        gload_lds16(Bg + rstep, Bsl2);
        Ag += 32; Bg += 32;
        __syncthreads();   // drains vmcnt: staging complete
        s16x8 af[4], bfr[4];
#pragma unroll
        for (int m = 0; m < 4; ++m)
            af[m] = *(const s16x8*)&As[mrow + m * 16][kfr];
#pragma unroll
        for (int n = 0; n < 4; ++n)
            bfr[n] = *(const s16x8*)&Bs[ncol + n * 16][kfr];
#pragma unroll
        for (int m = 0; m < 4; ++m)
#pragma unroll
            for (int n = 0; n < 4; ++n)
                acc[m][n] = __builtin_amdgcn_mfma_f32_16x16x32_bf16(
                    af[m], bfr[n], acc[m][n], 0, 0, 0);
        __syncthreads();   // all reads done before next stage
    }

    const int r0 = row0 + wr * 64 + ((lane >> 4) << 2);
    const int c0 = col0 + wc * 64 + (lane & 15);
#pragma unroll
    for (int n = 0; n < 4; ++n) {
        const int c = c0 + n * 16;
        const float bv = bias[c];
#pragma unroll
        for (int m = 0; m < 4; ++m) {
#pragma unroll
            for (int r = 0; r < 4; ++r) {
                const int row = r0 + m * 16 + r;
                if (row < Mvalid) {
                    float v = acc[m][n][r] + bv;
                    if (OUTBF)
                        ((ushort*)Cout)[(size_t)row * N + c] = f2b(v * scale);
                    else
                        ((float*)Cout)[(size_t)row * N + c] = v;
                }
            }
        }
    }
}

// ---------------- fused attention ----------------
// One block per (qchunk of 512 rows, b, h). 4 waves x 16 q-rows x 8 iters.
// Swapped QK^T -> in-register softmax; padded LDS (no bank conflicts);
// zero barriers in the main loop (wave-private P regions).
// q: [B*SQ][DE] bf16 (pre-scaled 1/8, bias fused); kv: [640][2048] bf16; o: bf16
__global__ __launch_bounds__(256, 4)
void attn(const ushort* __restrict__ q, const ushort* __restrict__ kv,
          ushort* __restrict__ o) {
    __shared__ ushort Ks[80][72];    // stride 144B = 9*16: aligned, ~2-way banks
    __shared__ ushort Vt[64][104];   // V^T; stride 208B = 13*16
    __shared__ ushort Ps[64][104];   // per-wave 16-row regions

    const int qc = blockIdx.x;       // 0..7
    const int bh = blockIdx.y;       // 0..127
    const int b = bh >> 4, h = bh & 15;
    const int tid = threadIdx.x, lane = tid & 63, wid = tid >> 6;
    const int g = lane >> 4, qi = lane & 15;
    const int kfr = g * 8;
    const int kvb = g * 4;

    const ushort* kbase = kv + (size_t)b * SKV * 2048 + h * 64;
    const ushort* vbase = kbase + 1024;

    // zero Vt pad cols 77..103 (disjoint from scatter region: no barrier needed)
    for (int i = tid; i < 64 * 27; i += 256) {
        int d = i / 27, c = 77 + i % 27;
        Vt[d][c] = 0;
    }
    // stage K rows 0..79 (pad rows clamp to row 76; masked in softmax)
    {
        int row = tid >> 3;
        const int cs = (tid & 7) * 8;
#pragma unroll
        for (int pass = 0; pass < 3; ++pass, row += 32)
            if (row < 80) {
                const int sr = row < SKV ? row : SKV - 1;
                *(uint4*)&Ks[row][cs] = *(const uint4*)(kbase + (size_t)sr * 2048 + cs);
            }
    }
    // stage V transposed (cols 0..76)
    for (int t = tid; t < SKV * 8; t += 256) {
        const int s = t >> 3, d8 = (t & 7) * 8;
        ushort tmp[8];
        *(uint4*)tmp = *(const uint4*)(vbase + (size_t)s * 2048 + d8);
#pragma unroll
        for (int j = 0; j < 8; ++j) Vt[d8 + j][s] = tmp[j];
    }
    __syncthreads();   // the only barrier

    const size_t qrow0 = (size_t)b * SQL + (size_t)qc * QCH;
    const ushort* qb = q + (qrow0 + wid * 16 + qi) * DE + h * 64 + kfr;

    for (int it = 0; it < QCH / 64; ++it) {
        // Q fragments (B-operand): row = qi, k = d
        const ushort* qp = qb + (size_t)it * 64 * DE;
        s16x8 aq0 = *(const s16x8*)qp;
        s16x8 aq1 = *(const s16x8*)(qp + 32);

        // S^T = K @ Q^T : lane holds S[q=qi][kv = n*16 + kvb + r]
        f32x4 accs[5] = {};
#pragma unroll
        for (int n = 0; n < 5; ++n) {
            s16x8 k0 = *(const s16x8*)&Ks[n * 16 + qi][kfr];
            s16x8 k1 = *(const s16x8*)&Ks[n * 16 + qi][kfr + 32];
            accs[n] = __builtin_amdgcn_mfma_f32_16x16x32_bf16(k0, aq0, accs[n], 0, 0, 0);
            accs[n] = __builtin_amdgcn_mfma_f32_16x16x32_bf16(k1, aq1, accs[n], 0, 0, 0);
        }

        // in-register softmax over the row's 77 cols (4 lanes share a row)
        float ev[5][4];
        float m = -1e30f;
#pragma unroll
        for (int n = 0; n < 5; ++n)
#pragma unroll
            for (int r = 0; r < 4; ++r) {
                float v = accs[n][r];
                v = (n * 16 + kvb + r < SKV) ? v : -1e30f;
                ev[n][r] = v;
                m = fmaxf(m, v);
            }
        m = fmaxf(m, __shfl_xor(m, 16));
        m = fmaxf(m, __shfl_xor(m, 32));
        float s = 0.f;
#pragma unroll
        for (int n = 0; n < 5; ++n)
#pragma unroll
            for (int r = 0; r < 4; ++r) {
                float e = __expf(ev[n][r] - m);
                ev[n][r] = e;
                s += e;
            }
        s += __shfl_xor(s, 16);
        s += __shfl_xor(s, 32);
        const float inv = 1.f / s;

        // write P (bf16) to this wave's Ps rows; cols 80..95 zeroed
        {
            ushort* pr = &Ps[wid * 16 + qi][0];
#pragma unroll
            for (int n = 0; n < 5; ++n) {
#pragma unroll
                for (int rp = 0; rp < 4; rp += 2) {
                    uint32_t u = (uint32_t)f2b(ev[n][rp] * inv) |
                                 ((uint32_t)f2b(ev[n][rp + 1] * inv) << 16);
                    *(uint32_t*)&pr[n * 16 + kvb + rp] = u;
                }
            }
            *(uint32_t*)&pr[80 + kvb] = 0;
            *(uint32_t*)&pr[80 + kvb + 2] = 0;
        }

        // O = P @ V  (K = 96, zero-padded); wave-private, no barrier
        f32x4 acco[4] = {};
#pragma unroll
        for (int kk = 0; kk < 3; ++kk) {
            s16x8 pa = *(const s16x8*)&Ps[wid * 16 + qi][kk * 32 + kfr];
#pragma unroll
            for (int n2 = 0; n2 < 4; ++n2) {
                s16x8 vb = *(const s16x8*)&Vt[n2 * 16 + qi][kk * 32 + kfr];
                acco[n2] = __builtin_amdgcn_mfma_f32_16x16x32_bf16(pa, vb, acco[n2], 0, 0, 0);
            }
        }
        const size_t orow = qrow0 + it * 64 + wid * 16 + kvb;
#pragma unroll
        for (int n2 = 0; n2 < 4; ++n2)
#pragma unroll
            for (int r = 0; r < 4; ++r)
                o[(orow + r) * DE + h * 64 + n2 * 16 + qi] = f2b(acco[n2][r]);
    }
}

extern "C" void kernel_launch(void* const* d_in, const int* in_sizes, int n_in,
                              void* d_out, int out_size, void* d_ws, size_t ws_size,
                              hipStream_t stream) {
    const float* x = (const float*)d_in[0];
    const float* y = (const float*)d_in[1];
    const float* wq = (const float*)d_in[2];
    const float* bq = (const float*)d_in[3];
    const float* wk = (const float*)d_in[4];
    const float* bk = (const float*)d_in[5];
    const float* wv = (const float*)d_in[6];
    const float* bv = (const float*)d_in[7];
    const float* wo = (const float*)d_in[8];
    const float* bo = (const float*)d_in[9];
    float* out = (float*)d_out;

    char* ws = (char*)d_ws;
    ushort* x16 = (ushort*)ws;  ws += (size_t)32768 * 1024 * 2;  // reused as attn_out
    ushort* q16 = (ushort*)ws;  ws += (size_t)32768 * 1024 * 2;
    ushort* y16 = (ushort*)ws;  ws += (size_t)640 * 768 * 2;     // padded M
    ushort* kv16 = (ushort*)ws; ws += (size_t)640 * 2048 * 2;    // padded M
    ushort* wqt = (ushort*)ws;  ws += (size_t)1024 * 1024 * 2;
    ushort* wkvt = (ushort*)ws; ws += (size_t)2048 * 768 * 2;
    ushort* wot = (ushort*)ws;  ws += (size_t)1024 * 1024 * 2;
    float* bkv = (float*)ws;    ws += 2048 * 4;

    // converts
    cvt_f32_bf16<<<16384, 256, 0, stream>>>(x, x16, 33554432LL);
    cvt_f32_bf16<<<231, 256, 0, stream>>>(y, y16, 473088LL);
    // weight transposes ([K][N] fp32 -> [N][K] bf16)
    transpose_cvt<<<dim3(32, 32), dim3(32, 8), 0, stream>>>(wq, wqt, 1024, 1024);
    transpose_cvt<<<dim3(32, 24), dim3(32, 8), 0, stream>>>(wk, wkvt, 768, 1024);
    transpose_cvt<<<dim3(32, 24), dim3(32, 8), 0, stream>>>(wv, wkvt + (size_t)1024 * 768, 768, 1024);
    transpose_cvt<<<dim3(32, 32), dim3(32, 8), 0, stream>>>(wo, wot, 1024, 1024);
    pack_bias<<<8, 256, 0, stream>>>(bk, bv, bkv);
    // K/V projection (combined): [640]x[2048], K=768, valid M=616; 80 blocks
    gemm_bt<1><<<80, 256, 0, stream>>>(y16, wkvt, bkv, kv16, 640, 2048, 768, 616, 1.0f, 16);
    // Q projection, bias fused, pre-scaled by 1/sqrt(64); 2048 blocks
    gemm_bt<1><<<2048, 256, 0, stream>>>(x16, wqt, bq, q16, 32768, 1024, 1024, 32768, 0.125f, 8);
    // attention (attn_out aliases x16; x16 dead after Q-proj)
    attn<<<dim3(8, 128), 256, 0, stream>>>(q16, kv16, x16);
    // output projection -> fp32 out
    gemm_bt<0><<<2048, 256, 0, stream>>>(x16, wot, bo, out, 32768, 1024, 1024, 32768, 1.0f, 8);
}

// Round 3
// 498.113 us; speedup vs baseline: 1.2635x; 1.0556x over previous
//
#include <hip/hip_runtime.h>
#include <stdint.h>

#define NH 16
#define DH 64
#define DE 1024
#define DC 768
#define NB 8
#define SQL 4096
#define SKV 77
#define QCH 512

typedef __attribute__((ext_vector_type(8))) short s16x8;
typedef __attribute__((ext_vector_type(4))) float f32x4;

__device__ inline ushort f2b(float f) {
    union { float f; uint32_t u; } v; v.f = f;
    uint32_t u = v.u;
    uint32_t r = (u + 0x7FFFu + ((u >> 16) & 1u)) >> 16;
    return (ushort)r;
}

__device__ inline void gload_lds16(const void* g, void* l) {
    __builtin_amdgcn_global_load_lds(
        (const __attribute__((address_space(1))) void*)g,
        (__attribute__((address_space(3))) void*)l, 16, 0, 0);
}

// ---------------- fp32 -> bf16 convert (vectorized) ----------------
__global__ void cvt_f32_bf16(const float* __restrict__ in, ushort* __restrict__ out,
                             long long n) {
    long long i = ((long long)blockIdx.x * 256 + threadIdx.x) * 8;
    if (i >= n) return;
    float4 a = *(const float4*)(in + i);
    float4 b = *(const float4*)(in + i + 4);
    ushort4 r0 = make_ushort4(f2b(a.x), f2b(a.y), f2b(a.z), f2b(a.w));
    ushort4 r1 = make_ushort4(f2b(b.x), f2b(b.y), f2b(b.z), f2b(b.w));
    *(ushort4*)(out + i) = r0;
    *(ushort4*)(out + i + 4) = r1;
}

// ---------------- transpose + convert: in fp32 [K][N] -> out bf16 [N][K] ----
__global__ void transpose_cvt(const float* __restrict__ in, ushort* __restrict__ out,
                              int K, int N) {
    __shared__ float tile[32][33];
    const int tx = threadIdx.x, ty = threadIdx.y;      // (32, 8)
    const int bn = blockIdx.x * 32, bk = blockIdx.y * 32;
#pragma unroll
    for (int i = 0; i < 4; ++i)
        tile[ty + i * 8][tx] = in[(size_t)(bk + ty + i * 8) * N + bn + tx];
    __syncthreads();
#pragma unroll
    for (int i = 0; i < 4; ++i)
        out[(size_t)(bn + ty + i * 8) * K + bk + tx] = f2b(tile[tx][ty + i * 8]);
}

// ---------------- pack bk|bv into one 2048-float bias ----------------
__global__ void pack_bias(const float* __restrict__ bk, const float* __restrict__ bv,
                          float* __restrict__ bkv) {
    int i = blockIdx.x * 256 + threadIdx.x;
    if (i < 2048) bkv[i] = (i < 1024) ? bk[i] : bv[i - 1024];
}

// ---------------- 128x128 bf16 GEMM (m97 structure) for the small KV-proj ---
template <int OUTBF>
__global__ __launch_bounds__(256, 2)
void gemm_bt(const ushort* __restrict__ A, const ushort* __restrict__ Bt,
             const float* __restrict__ bias, void* __restrict__ Cout,
             int M, int N, int K, int Mvalid, float scale, int nby) {
    __shared__ ushort As[128][32];
    __shared__ ushort Bs[128][32];
    const int tid = threadIdx.x;
    const int lane = tid & 63, wid = tid >> 6;
    const int wr = wid >> 1, wc = wid & 1;
    const int l = blockIdx.x;
    const int q8 = gridDim.x >> 3;
    const int rm = (l & 7) * q8 + (l >> 3);
    const int row0 = (rm / nby) * 128, col0 = (rm % nby) * 128;

    const int srow = tid >> 2;
    const int sk = (tid & 3) * 8;
    const ushort* Ag = A + (size_t)(row0 + srow) * K + sk;
    const ushort* Bg = Bt + (size_t)(col0 + srow) * K + sk;
    ushort* Asl = &As[srow][sk];
    ushort* Asl2 = &As[srow + 64][sk];
    ushort* Bsl = &Bs[srow][sk];
    ushort* Bsl2 = &Bs[srow + 64][sk];
    const size_t rstep = (size_t)64 * K;

    f32x4 acc[4][4] = {};
    const int mrow = wr * 64 + (lane & 15);
    const int ncol = wc * 64 + (lane & 15);
    const int kfr = (lane >> 4) * 8;

    const int nk = K >> 5;
    for (int kt = 0; kt < nk; ++kt) {
        gload_lds16(Ag, Asl);
        gload_lds16(Ag + rstep, Asl2);
        gload_lds16(Bg, Bsl);
        gload_lds16(Bg + rstep, Bsl2);
        Ag += 32; Bg += 32;
        __syncthreads();
        s16x8 af[4], bfr[4];
#pragma unroll
        for (int m = 0; m < 4; ++m)
            af[m] = *(const s16x8*)&As[mrow + m * 16][kfr];
#pragma unroll
        for (int n = 0; n < 4; ++n)
            bfr[n] = *(const s16x8*)&Bs[ncol + n * 16][kfr];
#pragma unroll
        for (int m = 0; m < 4; ++m)
#pragma unroll
            for (int n = 0; n < 4; ++n)
                acc[m][n] = __builtin_amdgcn_mfma_f32_16x16x32_bf16(
                    af[m], bfr[n], acc[m][n], 0, 0, 0);
        __syncthreads();
    }

    const int r0 = row0 + wr * 64 + ((lane >> 4) << 2);
    const int c0 = col0 + wc * 64 + (lane & 15);
#pragma unroll
    for (int n = 0; n < 4; ++n) {
        const int c = c0 + n * 16;
        const float bv = bias[c];
#pragma unroll
        for (int m = 0; m < 4; ++m) {
#pragma unroll
            for (int r = 0; r < 4; ++r) {
                const int row = r0 + m * 16 + r;
                if (row < Mvalid) {
                    float v = acc[m][n][r] + bv;
                    if (OUTBF)
                        ((ushort*)Cout)[(size_t)row * N + c] = f2b(v * scale);
                    else
                        ((float*)Cout)[(size_t)row * N + c] = v;
                }
            }
        }
    }
}

// ---------------- 256x256 BK=64 8-wave GEMM: T2 swizzle + T3/T4 counted vmcnt
// A: [M][K] bf16, Bt: [N][K] bf16. M, N, K multiples of 256/256/64; nt >= 2.
// LDS 128 KB double-buffered. Grid 1-D, XCD-chunked (gridDim % 8 == 0).
template <int OUTBF>
__global__ __launch_bounds__(512, 2)
void gemm256(const ushort* __restrict__ A, const ushort* __restrict__ Bt,
             const float* __restrict__ bias, void* __restrict__ Cout,
             int N, int K, float scale, int nby) {
    __shared__ ushort lds[2][2][256 * 64];   // [buf][0=A,1=B][row*64 + col]
    const int tid = threadIdx.x, lane = tid & 63;
    const int wid = tid >> 6, wr = wid >> 2, wc = wid & 3;   // 2M x 4N waves
    const int l = blockIdx.x, q8 = gridDim.x >> 3;
    const int rm = (l & 7) * q8 + (l >> 3);
    const int row0 = (rm / nby) * 256, col0 = (rm % nby) * 256;

    // staging: chunk cidx = j*512 + tid -> row = cidx>>3, colchunk = tid&7.
    // LDS linear dest; source column pre-swizzled with (row&7)  [rule #21]
    const int sr = tid >> 3;                         // 0..63 (+ j*64)
    const int scx = ((tid & 7) ^ (sr & 7)) * 8;      // swizzled k-elem offset
    const ushort* Agp = A + (size_t)(row0 + sr) * K + scx;
    const ushort* Bgp = Bt + (size_t)(col0 + sr) * K + scx;

    const int nt = K >> 6;

    auto STAGE = [&](int t, int b) {
#pragma unroll
        for (int j = 0; j < 4; ++j)
            gload_lds16(Agp + (size_t)j * 64 * K + t * 64,
                        &lds[b][0][(j * 512 + tid) * 8]);
#pragma unroll
        for (int j = 0; j < 4; ++j)
            gload_lds16(Bgp + (size_t)j * 64 * K + t * 64,
                        &lds[b][1][(j * 512 + tid) * 8]);
    };

    // fragment read offsets (swizzled to match stage: chunk' = chunk ^ (row&7))
    const int fr = lane & 15, fk = lane >> 4;
    const int xk0 = ((fk) ^ (fr & 7)) * 16;          // byte offset, k-half 0
    const int xk1 = ((fk + 4) ^ (fr & 7)) * 16;      // byte offset, k-half 1

    f32x4 acc[8][4] = {};

    STAGE(0, 0);
    STAGE(1, 1);
    asm volatile("s_waitcnt vmcnt(8)" ::: "memory");   // tile 0 resident
    __builtin_amdgcn_s_barrier();
    __builtin_amdgcn_sched_barrier(0);

    for (int t = 0; t < nt; ++t) {
        const char* Ab = (const char*)&lds[t & 1][0][0];
        const char* Bb = (const char*)&lds[t & 1][1][0];
        s16x8 afrag[4][2], bfrag[4][2];
#pragma unroll
        for (int n = 0; n < 4; ++n) {
            const int br = (wc * 64 + n * 16 + fr) * 128;
            bfrag[n][0] = *(const s16x8*)(Bb + br + xk0);
            bfrag[n][1] = *(const s16x8*)(Bb + br + xk1);
        }
#pragma unroll
        for (int m = 0; m < 4; ++m) {
            const int ar = (wr * 128 + m * 16 + fr) * 128;
            afrag[m][0] = *(const s16x8*)(Ab + ar + xk0);
            afrag[m][1] = *(const s16x8*)(Ab + ar + xk1);
        }
        __builtin_amdgcn_s_setprio(1);
#pragma unroll
        for (int m = 0; m < 4; ++m)
#pragma unroll
            for (int n = 0; n < 4; ++n) {
                acc[m][n] = __builtin_amdgcn_mfma_f32_16x16x32_bf16(
                    afrag[m][0], bfrag[n][0], acc[m][n], 0, 0, 0);
                acc[m][n] = __builtin_amdgcn_mfma_f32_16x16x32_bf16(
                    afrag[m][1], bfrag[n][1], acc[m][n], 0, 0, 0);
            }
        __builtin_amdgcn_s_setprio(0);
#pragma unroll
        for (int m = 0; m < 4; ++m) {
            const int ar = (wr * 128 + 64 + m * 16 + fr) * 128;
            afrag[m][0] = *(const s16x8*)(Ab + ar + xk0);
            afrag[m][1] = *(const s16x8*)(Ab + ar + xk1);
        }
        __builtin_amdgcn_s_setprio(1);
#pragma unroll
        for (int m = 0; m < 4; ++m)
#pragma unroll
            for (int n = 0; n < 4; ++n) {
                acc[4 + m][n] = __builtin_amdgcn_mfma_f32_16x16x32_bf16(
                    afrag[m][0], bfrag[n][0], acc[4 + m][n], 0, 0, 0);
                acc[4 + m][n] = __builtin_amdgcn_mfma_f32_16x16x32_bf16(
                    afrag[m][1], bfrag[n][1], acc[4 + m][n], 0, 0, 0);
            }
        __builtin_amdgcn_s_setprio(0);
        __builtin_amdgcn_sched_barrier(0);
        __builtin_amdgcn_s_barrier();            // all waves done reading buf
        __builtin_amdgcn_sched_barrier(0);
        if (t + 2 < nt) {
            STAGE(t + 2, t & 1);                 // safe: buf fully consumed
            asm volatile("s_waitcnt vmcnt(8)" ::: "memory");  // t+1 resident
        } else {
            asm volatile("s_waitcnt vmcnt(0)" ::: "memory");
        }
        __builtin_amdgcn_sched_barrier(0);
        __builtin_amdgcn_s_barrier();
        __builtin_amdgcn_sched_barrier(0);
    }

    // epilogue: C[row][col], row = r00 + m*16 + r, col = c00 + n*16
    const int r00 = row0 + wr * 128 + fk * 4;
    const int c00 = col0 + wc * 64 + fr;
#pragma unroll
    for (int n = 0; n < 4; ++n) {
        const int c = c00 + n * 16;
        const float bv = bias[c];
#pragma unroll
        for (int m = 0; m < 8; ++m) {
#pragma unroll
            for (int r = 0; r < 4; ++r) {
                const int row = r00 + m * 16 + r;
                const float v = (acc[m][n][r] + bv) * scale;
                if (OUTBF)
                    ((ushort*)Cout)[(size_t)row * N + c] = f2b(v);
                else
                    ((float*)Cout)[(size_t)row * N + c] = v;
            }
        }
    }
}

// ---------------- fused attention (unchanged from round 2) ----------------
__global__ __launch_bounds__(256, 4)
void attn(const ushort* __restrict__ q, const ushort* __restrict__ kv,
          ushort* __restrict__ o) {
    __shared__ ushort Ks[80][72];
    __shared__ ushort Vt[64][104];
    __shared__ ushort Ps[64][104];

    const int qc = blockIdx.x;
    const int bh = blockIdx.y;
    const int b = bh >> 4, h = bh & 15;
    const int tid = threadIdx.x, lane = tid & 63, wid = tid >> 6;
    const int g = lane >> 4, qi = lane & 15;
    const int kfr = g * 8;
    const int kvb = g * 4;

    const ushort* kbase = kv + (size_t)b * SKV * 2048 + h * 64;
    const ushort* vbase = kbase + 1024;

    for (int i = tid; i < 64 * 27; i += 256) {
        int d = i / 27, c = 77 + i % 27;
        Vt[d][c] = 0;
    }
    {
        int row = tid >> 3;
        const int cs = (tid & 7) * 8;
#pragma unroll
        for (int pass = 0; pass < 3; ++pass, row += 32)
            if (row < 80) {
                const int srw = row < SKV ? row : SKV - 1;
                *(uint4*)&Ks[row][cs] = *(const uint4*)(kbase + (size_t)srw * 2048 + cs);
            }
    }
    for (int t = tid; t < SKV * 8; t += 256) {
        const int s = t >> 3, d8 = (t & 7) * 8;
        ushort tmp[8];
        *(uint4*)tmp = *(const uint4*)(vbase + (size_t)s * 2048 + d8);
#pragma unroll
        for (int j = 0; j < 8; ++j) Vt[d8 + j][s] = tmp[j];
    }
    __syncthreads();

    const size_t qrow0 = (size_t)b * SQL + (size_t)qc * QCH;
    const ushort* qb = q + (qrow0 + wid * 16 + qi) * DE + h * 64 + kfr;

    for (int it = 0; it < QCH / 64; ++it) {
        const ushort* qp = qb + (size_t)it * 64 * DE;
        s16x8 aq0 = *(const s16x8*)qp;
        s16x8 aq1 = *(const s16x8*)(qp + 32);

        f32x4 accs[5] = {};
#pragma unroll
        for (int n = 0; n < 5; ++n) {
            s16x8 k0 = *(const s16x8*)&Ks[n * 16 + qi][kfr];
            s16x8 k1 = *(const s16x8*)&Ks[n * 16 + qi][kfr + 32];
            accs[n] = __builtin_amdgcn_mfma_f32_16x16x32_bf16(k0, aq0, accs[n], 0, 0, 0);
            accs[n] = __builtin_amdgcn_mfma_f32_16x16x32_bf16(k1, aq1, accs[n], 0, 0, 0);
        }

        float ev[5][4];
        float m = -1e30f;
#pragma unroll
        for (int n = 0; n < 5; ++n)
#pragma unroll
            for (int r = 0; r < 4; ++r) {
                float v = accs[n][r];
                v = (n * 16 + kvb + r < SKV) ? v : -1e30f;
                ev[n][r] = v;
                m = fmaxf(m, v);
            }
        m = fmaxf(m, __shfl_xor(m, 16));
        m = fmaxf(m, __shfl_xor(m, 32));
        float s = 0.f;
#pragma unroll
        for (int n = 0; n < 5; ++n)
#pragma unroll
            for (int r = 0; r < 4; ++r) {
                float e = __expf(ev[n][r] - m);
                ev[n][r] = e;
                s += e;
            }
        s += __shfl_xor(s, 16);
        s += __shfl_xor(s, 32);
        const float inv = 1.f / s;

        {
            ushort* pr = &Ps[wid * 16 + qi][0];
#pragma unroll
            for (int n = 0; n < 5; ++n) {
#pragma unroll
                for (int rp = 0; rp < 4; rp += 2) {
                    uint32_t u = (uint32_t)f2b(ev[n][rp] * inv) |
                                 ((uint32_t)f2b(ev[n][rp + 1] * inv) << 16);
                    *(uint32_t*)&pr[n * 16 + kvb + rp] = u;
                }
            }
            *(uint32_t*)&pr[80 + kvb] = 0;
            *(uint32_t*)&pr[80 + kvb + 2] = 0;
        }

        f32x4 acco[4] = {};
#pragma unroll
        for (int kk = 0; kk < 3; ++kk) {
            s16x8 pa = *(const s16x8*)&Ps[wid * 16 + qi][kk * 32 + kfr];
#pragma unroll
            for (int n2 = 0; n2 < 4; ++n2) {
                s16x8 vb = *(const s16x8*)&Vt[n2 * 16 + qi][kk * 32 + kfr];
                acco[n2] = __builtin_amdgcn_mfma_f32_16x16x32_bf16(pa, vb, acco[n2], 0, 0, 0);
            }
        }
        const size_t orow = qrow0 + it * 64 + wid * 16 + kvb;
#pragma unroll
        for (int n2 = 0; n2 < 4; ++n2)
#pragma unroll
            for (int r = 0; r < 4; ++r)
                o[(orow + r) * DE + h * 64 + n2 * 16 + qi] = f2b(acco[n2][r]);
    }
}

extern "C" void kernel_launch(void* const* d_in, const int* in_sizes, int n_in,
                              void* d_out, int out_size, void* d_ws, size_t ws_size,
                              hipStream_t stream) {
    const float* x = (const float*)d_in[0];
    const float* y = (const float*)d_in[1];
    const float* wq = (const float*)d_in[2];
    const float* bq = (const float*)d_in[3];
    const float* wk = (const float*)d_in[4];
    const float* bk = (const float*)d_in[5];
    const float* wv = (const float*)d_in[6];
    const float* bv = (const float*)d_in[7];
    const float* wo = (const float*)d_in[8];
    const float* bo = (const float*)d_in[9];
    float* out = (float*)d_out;

    char* ws = (char*)d_ws;
    ushort* x16 = (ushort*)ws;  ws += (size_t)32768 * 1024 * 2;  // reused as attn_out
    ushort* q16 = (ushort*)ws;  ws += (size_t)32768 * 1024 * 2;
    ushort* y16 = (ushort*)ws;  ws += (size_t)640 * 768 * 2;     // padded M
    ushort* kv16 = (ushort*)ws; ws += (size_t)640 * 2048 * 2;    // padded M
    ushort* wqt = (ushort*)ws;  ws += (size_t)1024 * 1024 * 2;
    ushort* wkvt = (ushort*)ws; ws += (size_t)2048 * 768 * 2;
    ushort* wot = (ushort*)ws;  ws += (size_t)1024 * 1024 * 2;
    float* bkv = (float*)ws;    ws += 2048 * 4;

    // converts
    cvt_f32_bf16<<<16384, 256, 0, stream>>>(x, x16, 33554432LL);
    cvt_f32_bf16<<<231, 256, 0, stream>>>(y, y16, 473088LL);
    // weight transposes ([K][N] fp32 -> [N][K] bf16)
    transpose_cvt<<<dim3(32, 32), dim3(32, 8), 0, stream>>>(wq, wqt, 1024, 1024);
    transpose_cvt<<<dim3(32, 24), dim3(32, 8), 0, stream>>>(wk, wkvt, 768, 1024);
    transpose_cvt<<<dim3(32, 24), dim3(32, 8), 0, stream>>>(wv, wkvt + (size_t)1024 * 768, 768, 1024);
    transpose_cvt<<<dim3(32, 32), dim3(32, 8), 0, stream>>>(wo, wot, 1024, 1024);
    pack_bias<<<8, 256, 0, stream>>>(bk, bv, bkv);
    // K/V projection (combined): [640]x[2048], K=768, valid M=616; 80 blocks
    gemm_bt<1><<<80, 256, 0, stream>>>(y16, wkvt, bkv, kv16, 640, 2048, 768, 616, 1.0f, 16);
    // Q projection (256^2 pipelined), bias fused, pre-scaled by 1/8; 512 blocks
    gemm256<1><<<512, 512, 0, stream>>>(x16, wqt, bq, q16, 1024, 1024, 0.125f, 4);
    // attention (attn_out aliases x16; x16 dead after Q-proj)
    attn<<<dim3(8, 128), 256, 0, stream>>>(q16, kv16, x16);
    // output projection -> fp32 out (256^2 pipelined)
    gemm256<0><<<512, 512, 0, stream>>>(x16, wot, bo, out, 1024, 1024, 1.0f, 4);
}